// Round 15
// baseline (682.420 us; speedup 1.0000x reference)
//
#include <hip/hip_runtime.h>
#include <cmath>

#define Ss 4096
#define NCh 16
#define CK 256

typedef unsigned short bfu;
typedef __bf16 bf16x8 __attribute__((ext_vector_type(8)));
typedef float f32x4 __attribute__((ext_vector_type(4)));
typedef unsigned short u16x8 __attribute__((ext_vector_type(8)));

__device__ __forceinline__ float bf2f(unsigned short u) {
    union { unsigned u32; float f; } v; v.u32 = ((unsigned)u) << 16; return v.f;
}
__device__ __forceinline__ unsigned short f2bf(float f) {
    union { float f; unsigned u; } v; v.f = f;
    unsigned r = v.u + 0x7fff + ((v.u >> 16) & 1);
    return (unsigned short)(r >> 16);
}

// async global->LDS, 16B per lane. lds base wave-uniform; g per-lane.
__device__ __forceinline__ void g2l16(void* lds, const void* g) {
    __builtin_amdgcn_global_load_lds(
        (const __attribute__((address_space(1))) void*)g,
        (__attribute__((address_space(3))) void*)lds, 16, 0, 0);
}

#define MFMA __builtin_amdgcn_mfma_f32_16x16x32_bf16

// ---------------------------------------------------------------------------
// RoPE tables, compact [s][f], f = d & 63 (4096 x 64 each).
// ---------------------------------------------------------------------------
__global__ void rope_table(float* __restrict__ cosT, float* __restrict__ sinT) {
    int id = blockIdx.x * 256 + threadIdx.x;      // 262144
    int f = id & 63, s = id >> 6;
    float e = (2.0f * (float)f) / 128.0f;
    float inv = 1.0f / powf(10000.0f, e);
    float ang = (float)s * inv;
    cosT[id] = cosf(ang);
    sinT[id] = sinf(ang);
}

// ---------------------------------------------------------------------------
// fp32 -> bf16 conversion. conv2: two buffers in one launch (x + Wqkv).
// ---------------------------------------------------------------------------
__global__ void conv2_bf16(const float* __restrict__ a, bfu* __restrict__ oa, int n4a,
                           const float* __restrict__ b, bfu* __restrict__ ob, int n4b) {
    const int total = n4a + n4b;
    for (int i = blockIdx.x * 256 + threadIdx.x; i < total; i += gridDim.x * 256) {
        const float* in; bfu* out; int j;
        if (i < n4a) { in = a; out = oa; j = i; }
        else         { in = b; out = ob; j = i - n4a; }
        float4 v = ((const float4*)in)[j];
        ushort4 o;
        o.x = f2bf(v.x); o.y = f2bf(v.y); o.z = f2bf(v.z); o.w = f2bf(v.w);
        ((ushort4*)out)[j] = o;
    }
}
__global__ void conv_bf16(const float* __restrict__ in, bfu* __restrict__ out, int n4) {
    for (int i = blockIdx.x * 256 + threadIdx.x; i < n4; i += gridDim.x * 256) {
        float4 v = ((const float4*)in)[i];
        ushort4 o;
        o.x = f2bf(v.x); o.y = f2bf(v.y); o.z = f2bf(v.z); o.w = f2bf(v.w);
        ((ushort4*)out)[i] = o;
    }
}

// ---------------------------------------------------------------------------
// 256x256 bf16 MFMA GEMM, 4 waves (2M x 2N), per-wave 128x128 output.
// Rationale: LDS fragment traffic per CU per K-tile = waves*(WM+WN)*BK*2B.
// 8-wave 128x64 = 192 KB (~= MFMA floor -> measured 30% util, rounds 6-14);
// 4-wave 128x128 = 128 KB (1.5x less) -> LDS clearly under MFMA floor.
// Cost: acc = 256 VGPR/wave (~390 total, no spill expected), 1 wave/SIMD.
// Per tile: readB(16) once; A streamed in 4 dbuf groups with counted
// lgkm(4) so group g+1's reads drain under group g's 32 MFMA.
// 2 barriers/tile; stage(T+2) into dead slot; tail vmcnt(16) certifies T+1
// (16 newest loads = T+2 stay in flight; never 0 mid-loop).
// Involution LDS swizzle (row&7 structure unchanged -> PMC-0 conflicts).
// XCD-aware bijective block swizzle. A[M][2048], B[N][2048] K-major bf16.
// Grid 1-D (nbx*nby), 256 thr. EPI=0: RoPE+elu+1 -> qb,kb,kT,vT. EPI=1: f32.
// ---------------------------------------------------------------------------
template<int EPI>
__global__ __launch_bounds__(256, 1) void gemm256(
    const bfu* __restrict__ A, const bfu* __restrict__ B, int nbx,
    const float* __restrict__ cosT, const float* __restrict__ sinT,
    bfu* __restrict__ qb, bfu* __restrict__ kb,
    bfu* __restrict__ kT, bfu* __restrict__ vT,
    float* __restrict__ outF)
{
    __shared__ bfu AsL[2 * 256 * 64];   // 65536 B
    __shared__ bfu BsL[2 * 256 * 64];   // 65536 B
    const int nwg = gridDim.x;
    const int q8 = nwg >> 3;
    const int swz = (blockIdx.x & 7) * q8 + (blockIdx.x >> 3);
    const int bm = (swz / nbx) * 256, bn = (swz % nbx) * 256;

    const int tid = threadIdx.x;
    const int wid = tid >> 6, lane = tid & 63;
    const int wm = wid >> 1, wn = wid & 1;
    const int l15 = lane & 15, l7 = lane & 7, lhi = lane >> 4;

    // staging: 256 thr x 16 B = 32 rows x 128 B per instruction; 8 instr/operand.
    // LDS dest linear; global source column pre-swizzled (involution = read XOR).
    const int rl = tid >> 3;                       // 0..31
    const int scol = ((tid & 7) ^ (rl & 7)) * 8;
    const bfu* Ab = A + (size_t)(bm + rl) * 2048 + scol;
    const bfu* Bb = B + (size_t)(bn + rl) * 2048 + scol;

    f32x4 acc[8][8] = {};                          // 256 VGPRs
    bf16x8 bfr[8][2];                              // B frags, whole tile
    bf16x8 av[2][2][2];                            // A dbuf [parity][mi2][ks]

    auto stageA = [&](int T) {
        bfu* d = AsL + (T & 1) * 16384 + wid * 512;
        const bfu* s = Ab + (size_t)T * 64;
#pragma unroll
        for (int i = 0; i < 8; ++i)
            g2l16(d + i * 2048, s + (size_t)i * 32 * 2048);
    };
    auto stageB = [&](int T) {
        bfu* d = BsL + (T & 1) * 16384 + wid * 512;
        const bfu* s = Bb + (size_t)T * 64;
#pragma unroll
        for (int i = 0; i < 8; ++i)
            g2l16(d + i * 2048, s + (size_t)i * 32 * 2048);
    };

    // prologue: tiles 0,1 staged (32 loads); certify tile 0 (16 left in flight)
    stageA(0); stageB(0);
    stageA(1); stageB(1);
    asm volatile("s_waitcnt vmcnt(16)" ::: "memory");
    __builtin_amdgcn_s_barrier();
    asm volatile("" ::: "memory");

    for (int T = 0; T < 32; ++T) {
        const char* Ax = (const char*)AsL + (T & 1) * 32768;
        const char* Bx = (const char*)BsL + (T & 1) * 32768;

        // read all B frags (16) + A group 0 (4)
#pragma unroll
        for (int ni = 0; ni < 8; ++ni)
#pragma unroll
            for (int ks = 0; ks < 2; ++ks)
                bfr[ni][ks] = *(const bf16x8*)(Bx + (wn * 128 + ni * 16 + l15) * 128 + (((ks * 4 + lhi) ^ l7) << 4));
#pragma unroll
        for (int mi2 = 0; mi2 < 2; ++mi2)
#pragma unroll
            for (int ks = 0; ks < 2; ++ks)
                av[0][mi2][ks] = *(const bf16x8*)(Ax + (wm * 128 + mi2 * 16 + l15) * 128 + (((ks * 4 + lhi) ^ l7) << 4));

#pragma unroll
        for (int g = 0; g < 4; ++g) {
            if (g < 3) {   // prefetch next A group into other parity
#pragma unroll
                for (int mi2 = 0; mi2 < 2; ++mi2)
#pragma unroll
                    for (int ks = 0; ks < 2; ++ks)
                        av[(g + 1) & 1][mi2][ks] = *(const bf16x8*)(Ax + (wm * 128 + ((g + 1) * 2 + mi2) * 16 + l15) * 128 + (((ks * 4 + lhi) ^ l7) << 4));
                asm volatile("s_waitcnt lgkmcnt(4)" ::: "memory");  // all but the 4 just-issued
            } else {
                asm volatile("s_waitcnt lgkmcnt(0)" ::: "memory");
            }
            __builtin_amdgcn_sched_barrier(0);
            __builtin_amdgcn_s_setprio(1);
#pragma unroll
            for (int mi2 = 0; mi2 < 2; ++mi2)
#pragma unroll
                for (int ni = 0; ni < 8; ++ni) {
                    acc[g * 2 + mi2][ni] = MFMA(av[g & 1][mi2][0], bfr[ni][0], acc[g * 2 + mi2][ni], 0, 0, 0);
                    acc[g * 2 + mi2][ni] = MFMA(av[g & 1][mi2][1], bfr[ni][1], acc[g * 2 + mi2][ni], 0, 0, 0);
                }
            __builtin_amdgcn_s_setprio(0);
        }

        __builtin_amdgcn_s_barrier();              // all waves' slot-T reads retired
        if (T < 30) {
            stageA(T + 2); stageB(T + 2);          // overwrite dead slot T&1
            asm volatile("s_waitcnt vmcnt(16)" ::: "memory");   // certify T+1
        } else if (T == 30) {
            asm volatile("s_waitcnt vmcnt(0)" ::: "memory");
        }
        __builtin_amdgcn_s_barrier();              // T+1 collectively visible
        asm volatile("" ::: "memory");
    }

    // ---------------- epilogue ----------------
    if constexpr (EPI == 0) {
        const int part = bn >> 11;             // 0=q 1=k 2=v (uniform per block)
#pragma unroll
        for (int mi = 0; mi < 8; ++mi) {
            const int m0 = bm + wm * 128 + mi * 16 + (lhi << 2);
            const int bq = m0 >> 12;
            const int sloc = m0 & 4095;
#pragma unroll
            for (int ni = 0; ni < 8; ++ni) {
                const int cp = (bn & 2047) + wn * 128 + ni * 16 + l15;  // col within part
                const int d = cp & 127;
                const int head = cp >> 7;
                const int f = d & 63;
                float vv[4];
#pragma unroll
                for (int r = 0; r < 4; ++r) {
                    float v = acc[mi][ni][r];
                    float p = __shfl_xor(v, 1);      // partner d^1 (lane^1)
                    if (part < 2) {
                        const int s = (m0 + r) & 4095;
                        float cc = cosT[s * 64 + f], sn = sinT[s * 64 + f];
                        float o = (d & 1) ? v * cc + p * sn : v * cc - p * sn;
                        v = o > 0.0f ? o + 1.0f : __expf(o);
                    }
                    vv[r] = v;
                }
                if (part == 0) {
#pragma unroll
                    for (int r = 0; r < 4; ++r)
                        qb[(size_t)(m0 + r) * 2048 + cp] = f2bf(vv[r]);
                } else if (part == 1) {
#pragma unroll
                    for (int r = 0; r < 4; ++r)
                        kb[(size_t)(m0 + r) * 2048 + cp] = f2bf(vv[r]);
                    ushort4 t4;
                    t4.x = f2bf(vv[0]); t4.y = f2bf(vv[1]); t4.z = f2bf(vv[2]); t4.w = f2bf(vv[3]);
                    *(ushort4*)(kT + ((size_t)(bq * 16 + head) * 128 + d) * 4096 + sloc) = t4;
                } else {
                    ushort4 t4;
                    t4.x = f2bf(vv[0]); t4.y = f2bf(vv[1]); t4.z = f2bf(vv[2]); t4.w = f2bf(vv[3]);
                    *(ushort4*)(vT + ((size_t)(bq * 16 + head) * 128 + d) * 4096 + sloc) = t4;
                }
            }
        }
    } else {
#pragma unroll
        for (int mi = 0; mi < 8; ++mi) {
            const int m0 = bm + wm * 128 + mi * 16 + (lhi << 2);
#pragma unroll
            for (int ni = 0; ni < 8; ++ni) {
                const int n = bn + wn * 128 + ni * 16 + l15;
#pragma unroll
                for (int r = 0; r < 4; ++r)
                    outF[(size_t)(m0 + r) * 2048 + n] = acc[mi][ni][r];
            }
        }
    }
}

// ---------------------------------------------------------------------------
// Per (b,h,c): S^T[e][d] = P(vT, kT) over chunk (K=256), + Zc[d] = sum_l k[l][d].
// Output Scb bf16 [batch][e][d]. Grid 512, 256 thr.  (round-6 version)
// ---------------------------------------------------------------------------
__global__ __launch_bounds__(256) void kv_outer_mfma(
    const bfu* __restrict__ vT, const bfu* __restrict__ kT,
    bfu* __restrict__ Scb, float* __restrict__ Zc)
{
    __shared__ bfu As[128 * 64];   // vT tile (e rows)
    __shared__ bfu Bs[128 * 64];   // kT tile (d rows)
    __shared__ float zS[128][2];
    const int batch = blockIdx.x;
    const int c = batch & 15, h = (batch >> 4) & 15, b = batch >> 8;
    const size_t fbase = (size_t)(b * 16 + h) * 128 * 4096 + c * 256;
    const int tid = threadIdx.x, wid = tid >> 6, lane = tid & 63;
    const int wr = wid >> 1, wc = wid & 1;
    const int srow = lane >> 3, scol = (lane & 7) * 8;
    f32x4 acc[4][4] = {};
    float zreg = 0.0f;
    const int zd = tid >> 1, zo = (tid & 1) * 32;

    for (int k0 = 0; k0 < 256; k0 += 64) {
        __syncthreads();
#pragma unroll
        for (int i = 0; i < 4; ++i) {
            const int r = i * 32 + wid * 8;
            g2l16(&As[r * 64], vT + fbase + (size_t)(r + srow) * 4096 + k0 + scol);
            g2l16(&Bs[r * 64], kT + fbase + (size_t)(r + srow) * 4096 + k0 + scol);
        }
        __syncthreads();
#pragma unroll
        for (int ks = 0; ks < 2; ++ks) {
            bf16x8 af[4], bfr[4];
#pragma unroll
            for (int mi = 0; mi < 4; ++mi)
                af[mi] = *(const bf16x8*)&As[(wr * 64 + mi * 16 + (lane & 15)) * 64 + ks * 32 + (lane >> 4) * 8];
#pragma unroll
            for (int ni = 0; ni < 4; ++ni)
                bfr[ni] = *(const bf16x8*)&Bs[(wc * 64 + ni * 16 + (lane & 15)) * 64 + ks * 32 + (lane >> 4) * 8];
#pragma unroll
            for (int mi = 0; mi < 4; ++mi)
#pragma unroll
                for (int ni = 0; ni < 4; ++ni)
                    acc[mi][ni] = MFMA(af[mi], bfr[ni], acc[mi][ni], 0, 0, 0);
        }
        // Z partial sums from kT tile (rows = d)
#pragma unroll
        for (int j = 0; j < 32; ++j) zreg += bf2f(Bs[zd * 64 + zo + j]);
    }
    zS[zd][tid & 1] = zreg;
    __syncthreads();
    if (tid < 128) Zc[(size_t)batch * 128 + tid] = zS[tid][0] + zS[tid][1];
    bfu* Sout = Scb + (size_t)batch * 16384;
#pragma unroll
    for (int mi = 0; mi < 4; ++mi)
#pragma unroll
        for (int ni = 0; ni < 4; ++ni) {
            const int d = wc * 64 + ni * 16 + (lane & 15);
#pragma unroll
            for (int r = 0; r < 4; ++r) {
                const int e = wr * 64 + mi * 16 + ((lane >> 4) << 2) + r;
                Sout[e * 128 + d] = f2bf(acc[mi][ni][r]);
            }
        }
}

// ---------------------------------------------------------------------------
// Exclusive prefixes over chunks (in place). Scb bf16 (fp32 running sum).
// ---------------------------------------------------------------------------
__global__ void prefix_Sb(bfu* __restrict__ Scb) {
    size_t idx = (size_t)blockIdx.x * 256 + threadIdx.x;  // 32*16384
    size_t bh = idx >> 14, de = idx & 16383;
    bfu* p = Scb + bh * (size_t)NCh * 16384 + de;
    float run = 0.0f;
#pragma unroll
    for (int c = 0; c < NCh; ++c) {
        float t = bf2f(p[(size_t)c * 16384]);
        p[(size_t)c * 16384] = f2bf(run);
        run += t;
    }
}
__global__ void prefix_Z(float* __restrict__ Zc) {
    size_t idx = (size_t)blockIdx.x * 256 + threadIdx.x;  // 32*128
    size_t bh = idx >> 7, d = idx & 127;
    float* p = Zc + bh * (size_t)NCh * 128 + d;
    float run = 0.0f;
#pragma unroll
    for (int c = 0; c < NCh; ++c) {
        float t = p[(size_t)c * 128];
        p[(size_t)c * 128] = run;
        run += t;
    }
}

// ---------------------------------------------------------------------------
// MFMA chunk attention. Grid (2 halves, 512 batch), 256 thr / 4 waves (2x2).
// ---------------------------------------------------------------------------
__global__ __launch_bounds__(256) void chunk_mfma(
    const bfu* __restrict__ qb, const bfu* __restrict__ kb,
    const bfu* __restrict__ vT, const bfu* __restrict__ Scb,
    const float* __restrict__ Zc, bfu* __restrict__ ao)
{
    __shared__ bfu shrd[16384];    // k tile [m][128] / vT tile [e][128] / S^T tile
    __shared__ bfu attL[16384];    // att [l][m] bf16, byte ^ ((l&7)<<4)
    __shared__ float Zs[128];
    __shared__ float denS[128][2];
    const int half = blockIdx.x, batch = blockIdx.y;
    const int c = batch & 15, h = (batch >> 4) & 15, b = batch >> 8;
    const int row0 = b * Ss + c * CK;
    const int tid = threadIdx.x, wid = tid >> 6, lane = tid & 63;
    const int wr = wid >> 1, wc = wid & 1;
    const int sr = lane >> 4, sc8 = (lane & 15) * 8;
    if (tid < 128) Zs[tid] = Zc[(size_t)batch * 128 + tid];

    bf16x8 qf[4][4];
    {
        const bfu* qrow = qb + (size_t)(row0 + half * 128 + wr * 64 + (lane & 15)) * 2048
                          + h * 128 + (lane >> 4) * 8;
#pragma unroll
        for (int mi = 0; mi < 4; ++mi)
#pragma unroll
            for (int ks = 0; ks < 4; ++ks)
                qf[mi][ks] = *(const bf16x8*)(qrow + (size_t)mi * 16 * 2048 + ks * 32);
    }
    f32x4 num[4][4] = {};
    float den_reg = 0.0f;
    const int dl = tid >> 1, dc0 = (tid & 1) * 64;

    for (int kb_ = 0; kb_ <= half; ++kb_) {
        __syncthreads();
#pragma unroll
        for (int i = 0; i < 8; ++i) {
            const int r = i * 16 + wid * 4;
            g2l16(&shrd[r * 128], kb + (size_t)(row0 + kb_ * 128 + r + sr) * 2048 + h * 128 + sc8);
        }
        __syncthreads();
        f32x4 attacc[4][4] = {};
#pragma unroll
        for (int ks = 0; ks < 4; ++ks) {
            bf16x8 bfr[4];
#pragma unroll
            for (int ni = 0; ni < 4; ++ni)
                bfr[ni] = *(const bf16x8*)&shrd[(wc * 64 + ni * 16 + (lane & 15)) * 128 + ks * 32 + (lane >> 4) * 8];
#pragma unroll
            for (int mi = 0; mi < 4; ++mi)
#pragma unroll
                for (int ni = 0; ni < 4; ++ni)
                    attacc[mi][ni] = MFMA(qf[mi][ks], bfr[ni], attacc[mi][ni], 0, 0, 0);
        }
        __syncthreads();
#pragma unroll
        for (int i = 0; i < 8; ++i) {
            const int r = i * 16 + wid * 4;
            g2l16(&shrd[r * 128],
                  vT + ((size_t)(b * 16 + h) * 128 + r + sr) * 4096 + c * 256 + kb_ * 128 + sc8);
        }
        const bool needmask = (kb_ == half);
#pragma unroll
        for (int mi = 0; mi < 4; ++mi)
#pragma unroll
            for (int ni = 0; ni < 4; ++ni) {
                const int l0 = wr * 64 + mi * 16 + ((lane >> 4) << 2);
                const int m = wc * 64 + ni * 16 + (lane & 15);
#pragma unroll
                for (int r = 0; r < 4; ++r) {
                    const int l = l0 + r;
                    float v = attacc[mi][ni][r];
                    if (needmask && (half * 128 + l) < (kb_ * 128 + m)) v = 0.0f;
                    const int byte = (l * 256 + m * 2) ^ ((l & 7) << 4);
                    *(bfu*)((char*)attL + byte) = f2bf(v);
                }
            }
        __syncthreads();
#pragma unroll
        for (int ks = 0; ks < 4; ++ks) {
            bf16x8 af[4], bfr[4];
#pragma unroll
            for (int mi = 0; mi < 4; ++mi) {
                const int l = wr * 64 + mi * 16 + (lane & 15);
                const int byte = (l * 256 + (ks * 32 + (lane >> 4) * 8) * 2) ^ ((l & 7) << 4);
                af[mi] = *(const bf16x8*)((const char*)attL + byte);
            }
#pragma unroll
            for (int ni = 0; ni < 4; ++ni)
                bfr[ni] = *(const bf16x8*)&shrd[(wc * 64 + ni * 16 + (lane & 15)) * 128 + ks * 32 + (lane >> 4) * 8];
#pragma unroll
            for (int mi = 0; mi < 4; ++mi)
#pragma unroll
                for (int ni = 0; ni < 4; ++ni)
                    num[mi][ni] = MFMA(af[mi], bfr[ni], num[mi][ni], 0, 0, 0);
        }
#pragma unroll
        for (int j8 = 0; j8 < 8; ++j8) {
            const int byte = (dl * 256 + (dc0 + j8 * 8) * 2) ^ ((dl & 7) << 4);
            u16x8 a = *(const u16x8*)((const char*)attL + byte);
#pragma unroll
            for (int jj = 0; jj < 8; ++jj) den_reg += bf2f(a[jj]);
        }
    }
    __syncthreads();
#pragma unroll
    for (int i = 0; i < 8; ++i) {
        const int r = i * 16 + wid * 4;
        g2l16(&shrd[r * 128], Scb + (size_t)batch * 16384 + (size_t)(r + sr) * 128 + sc8);
    }
    __syncthreads();
#pragma unroll
    for (int ks = 0; ks < 4; ++ks) {
        bf16x8 bfr[4];
#pragma unroll
        for (int ni = 0; ni < 4; ++ni)
            bfr[ni] = *(const bf16x8*)&shrd[(wc * 64 + ni * 16 + (lane & 15)) * 128 + ks * 32 + (lane >> 4) * 8];
#pragma unroll
        for (int mi = 0; mi < 4; ++mi)
#pragma unroll
            for (int ni = 0; ni < 4; ++ni)
                num[mi][ni] = MFMA(qf[mi][ks], bfr[ni], num[mi][ni], 0, 0, 0);
    }
    {
        const bfu* qrow = qb + (size_t)(row0 + half * 128 + dl) * 2048 + h * 128 + dc0;
#pragma unroll
        for (int j8 = 0; j8 < 8; ++j8) {
            u16x8 a = *(const u16x8*)(qrow + j8 * 8);
#pragma unroll
            for (int jj = 0; jj < 8; ++jj) den_reg += bf2f(a[jj]) * Zs[dc0 + j8 * 8 + jj];
        }
    }
    denS[dl][tid & 1] = den_reg;
    __syncthreads();
    bfu* aop = ao + (size_t)(row0 + half * 128) * 2048 + h * 128;
#pragma unroll
    for (int mi = 0; mi < 4; ++mi)
#pragma unroll
        for (int ni = 0; ni < 4; ++ni) {
            const int e = wc * 64 + ni * 16 + (lane & 15);
#pragma unroll
            for (int r = 0; r < 4; ++r) {
                const int l = wr * 64 + mi * 16 + ((lane >> 4) << 2) + r;
                float dv = denS[l][0] + denS[l][1];
                dv = dv > 1e-6f ? dv : 1e-6f;
                aop[(size_t)l * 2048 + e] = f2bf(num[mi][ni][r] / dv);
            }
        }
}

// ---------------------------------------------------------------------------
extern "C" void kernel_launch(void* const* d_in, const int* in_sizes, int n_in,
                              void* d_out, int out_size, void* d_ws, size_t ws_size,
                              hipStream_t stream)
{
    const float* x    = (const float*)d_in[0];
    const float* Wqkv = (const float*)d_in[1];
    const float* Wout = (const float*)d_in[2];
    float* out = (float*)d_out;
    char* ws = (char*)d_ws;

    // byte layout (~202.3 MB total, proven safe in rounds 2-14):
    bfu* xb   = (bfu*)(ws);                    // 16,777,216 elems; ao aliases after qkv gemm
    bfu* ao   = (bfu*)(ws);
    bfu* wqb  = (bfu*)(ws + 33554432);         // 12,582,912 elems; wob aliases after
    bfu* wob  = (bfu*)(ws + 33554432);         //  4,194,304 elems
    float* cosT = (float*)(ws + 58720256);     // 262,144
    float* sinT = (float*)(ws + 59768832);     // 262,144
    bfu* Scb  = (bfu*)(ws + 60817408);         // 8,388,608 elems (bf16 S^T prefix states)
    float* Zc = (float*)(ws + 77594624);       // 65,536
    bfu* qb   = (bfu*)(ws + 77856768);         // 16,777,216
    bfu* kb   = (bfu*)(ws + 111411200);        // 16,777,216
    bfu* kTb  = (bfu*)(ws + 144965632);        // 16,777,216
    bfu* vTb  = (bfu*)(ws + 178520064);        // 16,777,216  (end 212,074,496)

    rope_table<<<1024, 256, 0, stream>>>(cosT, sinT);
    conv2_bf16<<<2048, 256, 0, stream>>>(x, xb, 4194304, Wqkv, wqb, 3145728);
    // qkv: M=8192, N=6144 -> grid 24*32=768 (768%8==0, swizzle bijective)
    gemm256<0><<<768, 256, 0, stream>>>(xb, wqb, 24, cosT, sinT, qb, kb, kTb, vTb, nullptr);
    conv_bf16<<<1024, 256, 0, stream>>>(Wout, wob, 1048576);   // xb dead now
    kv_outer_mfma<<<512, 256, 0, stream>>>(vTb, kTb, Scb, Zc);
    prefix_Z<<<16, 256, 0, stream>>>(Zc);
    prefix_Sb<<<2048, 256, 0, stream>>>(Scb);
    chunk_mfma<<<dim3(2, 512), 256, 0, stream>>>(qb, kb, vTb, Scb, Zc, ao);
    // out: M=8192, N=2048 -> grid 8*32=256 (256%8==0)
    gemm256<1><<<256, 256, 0, stream>>>(ao, wob, 8, nullptr, nullptr, nullptr, nullptr, nullptr, nullptr, out);
}

// Round 16
// 469.277 us; speedup vs baseline: 1.4542x; 1.4542x over previous
//
#include <hip/hip_runtime.h>
#include <cmath>

#define Ss 4096
#define NCh 16
#define CK 256

typedef unsigned short bfu;
typedef __bf16 bf16x8 __attribute__((ext_vector_type(8)));
typedef float f32x4 __attribute__((ext_vector_type(4)));
typedef unsigned short u16x8 __attribute__((ext_vector_type(8)));

__device__ __forceinline__ float bf2f(unsigned short u) {
    union { unsigned u32; float f; } v; v.u32 = ((unsigned)u) << 16; return v.f;
}
__device__ __forceinline__ unsigned short f2bf(float f) {
    union { float f; unsigned u; } v; v.f = f;
    unsigned r = v.u + 0x7fff + ((v.u >> 16) & 1);
    return (unsigned short)(r >> 16);
}

// async global->LDS, 16B per lane. lds base wave-uniform; g per-lane.
__device__ __forceinline__ void g2l16(void* lds, const void* g) {
    __builtin_amdgcn_global_load_lds(
        (const __attribute__((address_space(1))) void*)g,
        (__attribute__((address_space(3))) void*)lds, 16, 0, 0);
}

#define MFMA __builtin_amdgcn_mfma_f32_16x16x32_bf16

// ---------------------------------------------------------------------------
// RoPE tables, compact [s][f], f = d & 63 (4096 x 64 each).
// ---------------------------------------------------------------------------
__global__ void rope_table(float* __restrict__ cosT, float* __restrict__ sinT) {
    int id = blockIdx.x * 256 + threadIdx.x;      // 262144
    int f = id & 63, s = id >> 6;
    float e = (2.0f * (float)f) / 128.0f;
    float inv = 1.0f / powf(10000.0f, e);
    float ang = (float)s * inv;
    cosT[id] = cosf(ang);
    sinT[id] = sinf(ang);
}

// ---------------------------------------------------------------------------
// fp32 -> bf16 conversion. conv2: two buffers in one launch (x + Wqkv).
// ---------------------------------------------------------------------------
__global__ void conv2_bf16(const float* __restrict__ a, bfu* __restrict__ oa, int n4a,
                           const float* __restrict__ b, bfu* __restrict__ ob, int n4b) {
    const int total = n4a + n4b;
    for (int i = blockIdx.x * 256 + threadIdx.x; i < total; i += gridDim.x * 256) {
        const float* in; bfu* out; int j;
        if (i < n4a) { in = a; out = oa; j = i; }
        else         { in = b; out = ob; j = i - n4a; }
        float4 v = ((const float4*)in)[j];
        ushort4 o;
        o.x = f2bf(v.x); o.y = f2bf(v.y); o.z = f2bf(v.z); o.w = f2bf(v.w);
        ((ushort4*)out)[j] = o;
    }
}
__global__ void conv_bf16(const float* __restrict__ in, bfu* __restrict__ out, int n4) {
    for (int i = blockIdx.x * 256 + threadIdx.x; i < n4; i += gridDim.x * 256) {
        float4 v = ((const float4*)in)[i];
        ushort4 o;
        o.x = f2bf(v.x); o.y = f2bf(v.y); o.z = f2bf(v.z); o.w = f2bf(v.w);
        ((ushort4*)out)[i] = o;
    }
}

// ---------------------------------------------------------------------------
// 256x256 bf16 MFMA GEMM (round-6/12 version, best measured). BK=64, 8 waves
// (2M x 4N), per-wave 128x64. 2-slot dbuf (128 KB). Region-death pipeline:
//   ph0: read A(mi0-3)+B(ni0-1), MFMA q00
//   ph1: read B(ni2-3), MFMA q01, BARRIER (B[T] dead)
//   ph2: read A(mi4-7), stage B(T+2) -> same slot, MFMA q10, BARRIER (A[T] dead)
//   ph3: stage A(T+2), MFMA q11, vmcnt(8) (certify T+1), BARRIER
// Involution LDS swizzle (linear gload_lds dest + pre-swizzled global source,
// read XOR) -- PMC-verified 0 conflicts. XCD-aware bijective block swizzle.
// A[M][2048], B[N][2048] K-major bf16. Grid 1-D (nbx*nby), 512 thr.
// EPI=0: fused RoPE+elu+1 -> qb,kb,kT,vT.  EPI=1: fp32 C store.
// ---------------------------------------------------------------------------
template<int EPI>
__global__ __launch_bounds__(512) void gemm256(
    const bfu* __restrict__ A, const bfu* __restrict__ B, int nbx,
    const float* __restrict__ cosT, const float* __restrict__ sinT,
    bfu* __restrict__ qb, bfu* __restrict__ kb,
    bfu* __restrict__ kT, bfu* __restrict__ vT,
    float* __restrict__ outF)
{
    __shared__ bfu AsL[2 * 256 * 64];   // 65536 B
    __shared__ bfu BsL[2 * 256 * 64];   // 65536 B
    const int nwg = gridDim.x;
    const int q8 = nwg >> 3;
    const int swz = (blockIdx.x & 7) * q8 + (blockIdx.x >> 3);
    const int bm = (swz / nbx) * 256, bn = (swz % nbx) * 256;

    const int tid = threadIdx.x;
    const int wid = tid >> 6, lane = tid & 63;
    const int wm = wid >> 2, wn = wid & 3;
    const int l15 = lane & 15, l7 = lane & 7, lhi = lane >> 4;

    const int rl = tid >> 3;
    const int scol = ((tid & 7) ^ (rl & 7)) * 8;
    const bfu* Ab = A + (size_t)(bm + rl) * 2048 + scol;
    const bfu* Bb = B + (size_t)(bn + rl) * 2048 + scol;

    f32x4 acc[8][4] = {};

    auto stageA = [&](int T) {
        bfu* d = AsL + (T & 1) * 16384 + wid * 512;
        const bfu* s = Ab + (size_t)T * 64;
        g2l16(d,         s);
        g2l16(d + 4096,  s + (size_t)64 * 2048);
        g2l16(d + 8192,  s + (size_t)128 * 2048);
        g2l16(d + 12288, s + (size_t)192 * 2048);
    };
    auto stageB = [&](int T) {
        bfu* d = BsL + (T & 1) * 16384 + wid * 512;
        const bfu* s = Bb + (size_t)T * 64;
        g2l16(d,         s);
        g2l16(d + 4096,  s + (size_t)64 * 2048);
        g2l16(d + 8192,  s + (size_t)128 * 2048);
        g2l16(d + 12288, s + (size_t)192 * 2048);
    };

    // prologue: tiles 0,1 staged; certify tile 0 (vmcnt(8) leaves tile 1 in flight)
    stageA(0); stageB(0);
    stageA(1); stageB(1);
    asm volatile("s_waitcnt vmcnt(8)" ::: "memory");
    __builtin_amdgcn_s_barrier();
    asm volatile("" ::: "memory");

    for (int T = 0; T < 32; ++T) {
        const char* Ax = (const char*)AsL + (T & 1) * 32768;
        const char* Bx = (const char*)BsL + (T & 1) * 32768;
        bf16x8 a0[4][2], a1[4][2], b0[2][2], b1[2][2];

        // ---- ph0: A(mi0-3) + B(ni0-1) reads; MFMA q00 ----
#pragma unroll
        for (int mi = 0; mi < 4; ++mi)
#pragma unroll
            for (int ks = 0; ks < 2; ++ks)
                a0[mi][ks] = *(const bf16x8*)(Ax + (wm * 128 + mi * 16 + l15) * 128 + (((ks * 4 + lhi) ^ l7) << 4));
#pragma unroll
        for (int ni = 0; ni < 2; ++ni)
#pragma unroll
            for (int ks = 0; ks < 2; ++ks)
                b0[ni][ks] = *(const bf16x8*)(Bx + (wn * 64 + ni * 16 + l15) * 128 + (((ks * 4 + lhi) ^ l7) << 4));
        asm volatile("s_waitcnt lgkmcnt(0)" ::: "memory");
        __builtin_amdgcn_sched_barrier(0);
        __builtin_amdgcn_s_setprio(1);
#pragma unroll
        for (int mi = 0; mi < 4; ++mi)
#pragma unroll
            for (int ni = 0; ni < 2; ++ni) {
                acc[mi][ni] = MFMA(a0[mi][0], b0[ni][0], acc[mi][ni], 0, 0, 0);
                acc[mi][ni] = MFMA(a0[mi][1], b0[ni][1], acc[mi][ni], 0, 0, 0);
            }
        __builtin_amdgcn_s_setprio(0);

        // ---- ph1: B(ni2-3) reads; MFMA q01; barrier = B[T] dead ----
#pragma unroll
        for (int ni = 0; ni < 2; ++ni)
#pragma unroll
            for (int ks = 0; ks < 2; ++ks)
                b1[ni][ks] = *(const bf16x8*)(Bx + (wn * 64 + (ni + 2) * 16 + l15) * 128 + (((ks * 4 + lhi) ^ l7) << 4));
        asm volatile("s_waitcnt lgkmcnt(0)" ::: "memory");
        __builtin_amdgcn_sched_barrier(0);
        __builtin_amdgcn_s_setprio(1);
#pragma unroll
        for (int mi = 0; mi < 4; ++mi)
#pragma unroll
            for (int ni = 0; ni < 2; ++ni) {
                acc[mi][ni + 2] = MFMA(a0[mi][0], b1[ni][0], acc[mi][ni + 2], 0, 0, 0);
                acc[mi][ni + 2] = MFMA(a0[mi][1], b1[ni][1], acc[mi][ni + 2], 0, 0, 0);
            }
        __builtin_amdgcn_s_setprio(0);
        __builtin_amdgcn_s_barrier();
        asm volatile("" ::: "memory");

        // ---- ph2: A(mi4-7) reads; stage B(T+2); MFMA q10; barrier = A[T] dead ----
#pragma unroll
        for (int mi = 0; mi < 4; ++mi)
#pragma unroll
            for (int ks = 0; ks < 2; ++ks)
                a1[mi][ks] = *(const bf16x8*)(Ax + (wm * 128 + (mi + 4) * 16 + l15) * 128 + (((ks * 4 + lhi) ^ l7) << 4));
        if (T < 30) stageB(T + 2);
        asm volatile("s_waitcnt lgkmcnt(0)" ::: "memory");
        __builtin_amdgcn_sched_barrier(0);
        __builtin_amdgcn_s_setprio(1);
#pragma unroll
        for (int mi = 0; mi < 4; ++mi)
#pragma unroll
            for (int ni = 0; ni < 2; ++ni) {
                acc[mi + 4][ni] = MFMA(a1[mi][0], b0[ni][0], acc[mi + 4][ni], 0, 0, 0);
                acc[mi + 4][ni] = MFMA(a1[mi][1], b0[ni][1], acc[mi + 4][ni], 0, 0, 0);
            }
        __builtin_amdgcn_s_setprio(0);
        __builtin_amdgcn_s_barrier();
        asm volatile("" ::: "memory");

        // ---- ph3: stage A(T+2); MFMA q11; certify T+1; barrier ----
        if (T < 30) stageA(T + 2);
        __builtin_amdgcn_s_setprio(1);
#pragma unroll
        for (int mi = 0; mi < 4; ++mi)
#pragma unroll
            for (int ni = 0; ni < 2; ++ni) {
                acc[mi + 4][ni + 2] = MFMA(a1[mi][0], b1[ni][0], acc[mi + 4][ni + 2], 0, 0, 0);
                acc[mi + 4][ni + 2] = MFMA(a1[mi][1], b1[ni][1], acc[mi + 4][ni + 2], 0, 0, 0);
            }
        __builtin_amdgcn_s_setprio(0);
        if (T < 30) { asm volatile("s_waitcnt vmcnt(8)" ::: "memory"); }
        else        { asm volatile("s_waitcnt vmcnt(0)" ::: "memory"); }
        __builtin_amdgcn_s_barrier();
        asm volatile("" ::: "memory");
    }

    // ---------------- epilogue ----------------
    if constexpr (EPI == 0) {
        const int part = bn >> 11;             // 0=q 1=k 2=v (uniform per block)
#pragma unroll
        for (int mi = 0; mi < 8; ++mi) {
            const int m0 = bm + wm * 128 + mi * 16 + (lhi << 2);
            const int bq = m0 >> 12;
            const int sloc = m0 & 4095;
#pragma unroll
            for (int ni = 0; ni < 4; ++ni) {
                const int cp = (bn & 2047) + wn * 64 + ni * 16 + l15;  // col within part
                const int d = cp & 127;
                const int head = cp >> 7;
                const int f = d & 63;
                float vv[4];
#pragma unroll
                for (int r = 0; r < 4; ++r) {
                    float v = acc[mi][ni][r];
                    float p = __shfl_xor(v, 1);      // partner d^1 (lane^1)
                    if (part < 2) {
                        const int s = (m0 + r) & 4095;
                        float cc = cosT[s * 64 + f], sn = sinT[s * 64 + f];
                        float o = (d & 1) ? v * cc + p * sn : v * cc - p * sn;
                        v = o > 0.0f ? o + 1.0f : __expf(o);
                    }
                    vv[r] = v;
                }
                if (part == 0) {
#pragma unroll
                    for (int r = 0; r < 4; ++r)
                        qb[(size_t)(m0 + r) * 2048 + cp] = f2bf(vv[r]);
                } else if (part == 1) {
#pragma unroll
                    for (int r = 0; r < 4; ++r)
                        kb[(size_t)(m0 + r) * 2048 + cp] = f2bf(vv[r]);
                    ushort4 t4;
                    t4.x = f2bf(vv[0]); t4.y = f2bf(vv[1]); t4.z = f2bf(vv[2]); t4.w = f2bf(vv[3]);
                    *(ushort4*)(kT + ((size_t)(bq * 16 + head) * 128 + d) * 4096 + sloc) = t4;
                } else {
                    ushort4 t4;
                    t4.x = f2bf(vv[0]); t4.y = f2bf(vv[1]); t4.z = f2bf(vv[2]); t4.w = f2bf(vv[3]);
                    *(ushort4*)(vT + ((size_t)(bq * 16 + head) * 128 + d) * 4096 + sloc) = t4;
                }
            }
        }
    } else {
#pragma unroll
        for (int mi = 0; mi < 8; ++mi) {
            const int m0 = bm + wm * 128 + mi * 16 + (lhi << 2);
#pragma unroll
            for (int ni = 0; ni < 4; ++ni) {
                const int n = bn + wn * 64 + ni * 16 + l15;
#pragma unroll
                for (int r = 0; r < 4; ++r)
                    outF[(size_t)(m0 + r) * 2048 + n] = acc[mi][ni][r];
            }
        }
    }
}

// ---------------------------------------------------------------------------
// Per (b,h,c): S^T[e][d] = P(vT, kT) over chunk (K=256), + Zc[d] = sum_l k[l][d].
// Output Scb bf16 [batch][e][d]. Grid 512, 256 thr.  (round-6 version)
// ---------------------------------------------------------------------------
__global__ __launch_bounds__(256) void kv_outer_mfma(
    const bfu* __restrict__ vT, const bfu* __restrict__ kT,
    bfu* __restrict__ Scb, float* __restrict__ Zc)
{
    __shared__ bfu As[128 * 64];   // vT tile (e rows)
    __shared__ bfu Bs[128 * 64];   // kT tile (d rows)
    __shared__ float zS[128][2];
    const int batch = blockIdx.x;
    const int c = batch & 15, h = (batch >> 4) & 15, b = batch >> 8;
    const size_t fbase = (size_t)(b * 16 + h) * 128 * 4096 + c * 256;
    const int tid = threadIdx.x, wid = tid >> 6, lane = tid & 63;
    const int wr = wid >> 1, wc = wid & 1;
    const int srow = lane >> 3, scol = (lane & 7) * 8;
    f32x4 acc[4][4] = {};
    float zreg = 0.0f;
    const int zd = tid >> 1, zo = (tid & 1) * 32;

    for (int k0 = 0; k0 < 256; k0 += 64) {
        __syncthreads();
#pragma unroll
        for (int i = 0; i < 4; ++i) {
            const int r = i * 32 + wid * 8;
            g2l16(&As[r * 64], vT + fbase + (size_t)(r + srow) * 4096 + k0 + scol);
            g2l16(&Bs[r * 64], kT + fbase + (size_t)(r + srow) * 4096 + k0 + scol);
        }
        __syncthreads();
#pragma unroll
        for (int ks = 0; ks < 2; ++ks) {
            bf16x8 af[4], bfr[4];
#pragma unroll
            for (int mi = 0; mi < 4; ++mi)
                af[mi] = *(const bf16x8*)&As[(wr * 64 + mi * 16 + (lane & 15)) * 64 + ks * 32 + (lane >> 4) * 8];
#pragma unroll
            for (int ni = 0; ni < 4; ++ni)
                bfr[ni] = *(const bf16x8*)&Bs[(wc * 64 + ni * 16 + (lane & 15)) * 64 + ks * 32 + (lane >> 4) * 8];
#pragma unroll
            for (int mi = 0; mi < 4; ++mi)
#pragma unroll
                for (int ni = 0; ni < 4; ++ni)
                    acc[mi][ni] = MFMA(af[mi], bfr[ni], acc[mi][ni], 0, 0, 0);
        }
        // Z partial sums from kT tile (rows = d)
#pragma unroll
        for (int j = 0; j < 32; ++j) zreg += bf2f(Bs[zd * 64 + zo + j]);
    }
    zS[zd][tid & 1] = zreg;
    __syncthreads();
    if (tid < 128) Zc[(size_t)batch * 128 + tid] = zS[tid][0] + zS[tid][1];
    bfu* Sout = Scb + (size_t)batch * 16384;
#pragma unroll
    for (int mi = 0; mi < 4; ++mi)
#pragma unroll
        for (int ni = 0; ni < 4; ++ni) {
            const int d = wc * 64 + ni * 16 + (lane & 15);
#pragma unroll
            for (int r = 0; r < 4; ++r) {
                const int e = wr * 64 + mi * 16 + ((lane >> 4) << 2) + r;
                Sout[e * 128 + d] = f2bf(acc[mi][ni][r]);
            }
        }
}

// ---------------------------------------------------------------------------
// Exclusive prefixes over chunks (in place). Scb bf16 (fp32 running sum).
// ---------------------------------------------------------------------------
__global__ void prefix_Sb(bfu* __restrict__ Scb) {
    size_t idx = (size_t)blockIdx.x * 256 + threadIdx.x;  // 32*16384
    size_t bh = idx >> 14, de = idx & 16383;
    bfu* p = Scb + bh * (size_t)NCh * 16384 + de;
    float run = 0.0f;
#pragma unroll
    for (int c = 0; c < NCh; ++c) {
        float t = bf2f(p[(size_t)c * 16384]);
        p[(size_t)c * 16384] = f2bf(run);
        run += t;
    }
}
__global__ void prefix_Z(float* __restrict__ Zc) {
    size_t idx = (size_t)blockIdx.x * 256 + threadIdx.x;  // 32*128
    size_t bh = idx >> 7, d = idx & 127;
    float* p = Zc + bh * (size_t)NCh * 128 + d;
    float run = 0.0f;
#pragma unroll
    for (int c = 0; c < NCh; ++c) {
        float t = p[(size_t)c * 128];
        p[(size_t)c * 128] = run;
        run += t;
    }
}

// ---------------------------------------------------------------------------
// MFMA chunk attention. Grid (2 halves, 512 batch), 256 thr / 4 waves (2x2).
// ---------------------------------------------------------------------------
__global__ __launch_bounds__(256) void chunk_mfma(
    const bfu* __restrict__ qb, const bfu* __restrict__ kb,
    const bfu* __restrict__ vT, const bfu* __restrict__ Scb,
    const float* __restrict__ Zc, bfu* __restrict__ ao)
{
    __shared__ bfu shrd[16384];    // k tile [m][128] / vT tile [e][128] / S^T tile
    __shared__ bfu attL[16384];    // att [l][m] bf16, byte ^ ((l&7)<<4)
    __shared__ float Zs[128];
    __shared__ float denS[128][2];
    const int half = blockIdx.x, batch = blockIdx.y;
    const int c = batch & 15, h = (batch >> 4) & 15, b = batch >> 8;
    const int row0 = b * Ss + c * CK;
    const int tid = threadIdx.x, wid = tid >> 6, lane = tid & 63;
    const int wr = wid >> 1, wc = wid & 1;
    const int sr = lane >> 4, sc8 = (lane & 15) * 8;
    if (tid < 128) Zs[tid] = Zc[(size_t)batch * 128 + tid];

    bf16x8 qf[4][4];
    {
        const bfu* qrow = qb + (size_t)(row0 + half * 128 + wr * 64 + (lane & 15)) * 2048
                          + h * 128 + (lane >> 4) * 8;
#pragma unroll
        for (int mi = 0; mi < 4; ++mi)
#pragma unroll
            for (int ks = 0; ks < 4; ++ks)
                qf[mi][ks] = *(const bf16x8*)(qrow + (size_t)mi * 16 * 2048 + ks * 32);
    }
    f32x4 num[4][4] = {};
    float den_reg = 0.0f;
    const int dl = tid >> 1, dc0 = (tid & 1) * 64;

    for (int kb_ = 0; kb_ <= half; ++kb_) {
        __syncthreads();
#pragma unroll
        for (int i = 0; i < 8; ++i) {
            const int r = i * 16 + wid * 4;
            g2l16(&shrd[r * 128], kb + (size_t)(row0 + kb_ * 128 + r + sr) * 2048 + h * 128 + sc8);
        }
        __syncthreads();
        f32x4 attacc[4][4] = {};
#pragma unroll
        for (int ks = 0; ks < 4; ++ks) {
            bf16x8 bfr[4];
#pragma unroll
            for (int ni = 0; ni < 4; ++ni)
                bfr[ni] = *(const bf16x8*)&shrd[(wc * 64 + ni * 16 + (lane & 15)) * 128 + ks * 32 + (lane >> 4) * 8];
#pragma unroll
            for (int mi = 0; mi < 4; ++mi)
#pragma unroll
                for (int ni = 0; ni < 4; ++ni)
                    attacc[mi][ni] = MFMA(qf[mi][ks], bfr[ni], attacc[mi][ni], 0, 0, 0);
        }
        __syncthreads();
#pragma unroll
        for (int i = 0; i < 8; ++i) {
            const int r = i * 16 + wid * 4;
            g2l16(&shrd[r * 128],
                  vT + ((size_t)(b * 16 + h) * 128 + r + sr) * 4096 + c * 256 + kb_ * 128 + sc8);
        }
        const bool needmask = (kb_ == half);
#pragma unroll
        for (int mi = 0; mi < 4; ++mi)
#pragma unroll
            for (int ni = 0; ni < 4; ++ni) {
                const int l0 = wr * 64 + mi * 16 + ((lane >> 4) << 2);
                const int m = wc * 64 + ni * 16 + (lane & 15);
#pragma unroll
                for (int r = 0; r < 4; ++r) {
                    const int l = l0 + r;
                    float v = attacc[mi][ni][r];
                    if (needmask && (half * 128 + l) < (kb_ * 128 + m)) v = 0.0f;
                    const int byte = (l * 256 + m * 2) ^ ((l & 7) << 4);
                    *(bfu*)((char*)attL + byte) = f2bf(v);
                }
            }
        __syncthreads();
#pragma unroll
        for (int ks = 0; ks < 4; ++ks) {
            bf16x8 af[4], bfr[4];
#pragma unroll
            for (int mi = 0; mi < 4; ++mi) {
                const int l = wr * 64 + mi * 16 + (lane & 15);
                const int byte = (l * 256 + (ks * 32 + (lane >> 4) * 8) * 2) ^ ((l & 7) << 4);
                af[mi] = *(const bf16x8*)((const char*)attL + byte);
            }
#pragma unroll
            for (int ni = 0; ni < 4; ++ni)
                bfr[ni] = *(const bf16x8*)&shrd[(wc * 64 + ni * 16 + (lane & 15)) * 128 + ks * 32 + (lane >> 4) * 8];
#pragma unroll
            for (int mi = 0; mi < 4; ++mi)
#pragma unroll
                for (int ni = 0; ni < 4; ++ni)
                    num[mi][ni] = MFMA(af[mi], bfr[ni], num[mi][ni], 0, 0, 0);
        }
#pragma unroll
        for (int j8 = 0; j8 < 8; ++j8) {
            const int byte = (dl * 256 + (dc0 + j8 * 8) * 2) ^ ((dl & 7) << 4);
            u16x8 a = *(const u16x8*)((const char*)attL + byte);
#pragma unroll
            for (int jj = 0; jj < 8; ++jj) den_reg += bf2f(a[jj]);
        }
    }
    __syncthreads();
#pragma unroll
    for (int i = 0; i < 8; ++i) {
        const int r = i * 16 + wid * 4;
        g2l16(&shrd[r * 128], Scb + (size_t)batch * 16384 + (size_t)(r + sr) * 128 + sc8);
    }
    __syncthreads();
#pragma unroll
    for (int ks = 0; ks < 4; ++ks) {
        bf16x8 bfr[4];
#pragma unroll
        for (int ni = 0; ni < 4; ++ni)
            bfr[ni] = *(const bf16x8*)&shrd[(wc * 64 + ni * 16 + (lane & 15)) * 128 + ks * 32 + (lane >> 4) * 8];
#pragma unroll
        for (int mi = 0; mi < 4; ++mi)
#pragma unroll
            for (int ni = 0; ni < 4; ++ni)
                num[mi][ni] = MFMA(qf[mi][ks], bfr[ni], num[mi][ni], 0, 0, 0);
    }
    {
        const bfu* qrow = qb + (size_t)(row0 + half * 128 + dl) * 2048 + h * 128 + dc0;
#pragma unroll
        for (int j8 = 0; j8 < 8; ++j8) {
            u16x8 a = *(const u16x8*)(qrow + j8 * 8);
#pragma unroll
            for (int jj = 0; jj < 8; ++jj) den_reg += bf2f(a[jj]) * Zs[dc0 + j8 * 8 + jj];
        }
    }
    denS[dl][tid & 1] = den_reg;
    __syncthreads();
    bfu* aop = ao + (size_t)(row0 + half * 128) * 2048 + h * 128;
#pragma unroll
    for (int mi = 0; mi < 4; ++mi)
#pragma unroll
        for (int ni = 0; ni < 4; ++ni) {
            const int e = wc * 64 + ni * 16 + (lane & 15);
#pragma unroll
            for (int r = 0; r < 4; ++r) {
                const int l = wr * 64 + mi * 16 + ((lane >> 4) << 2) + r;
                float dv = denS[l][0] + denS[l][1];
                dv = dv > 1e-6f ? dv : 1e-6f;
                aop[(size_t)l * 2048 + e] = f2bf(num[mi][ni][r] / dv);
            }
        }
}

// ---------------------------------------------------------------------------
extern "C" void kernel_launch(void* const* d_in, const int* in_sizes, int n_in,
                              void* d_out, int out_size, void* d_ws, size_t ws_size,
                              hipStream_t stream)
{
    const float* x    = (const float*)d_in[0];
    const float* Wqkv = (const float*)d_in[1];
    const float* Wout = (const float*)d_in[2];
    float* out = (float*)d_out;
    char* ws = (char*)d_ws;

    // byte layout (~202.3 MB total, proven safe in rounds 2-15):
    bfu* xb   = (bfu*)(ws);                    // 16,777,216 elems; ao aliases after qkv gemm
    bfu* ao   = (bfu*)(ws);
    bfu* wqb  = (bfu*)(ws + 33554432);         // 12,582,912 elems; wob aliases after
    bfu* wob  = (bfu*)(ws + 33554432);         //  4,194,304 elems
    float* cosT = (float*)(ws + 58720256);     // 262,144
    float* sinT = (float*)(ws + 59768832);     // 262,144
    bfu* Scb  = (bfu*)(ws + 60817408);         // 8,388,608 elems (bf16 S^T prefix states)
    float* Zc = (float*)(ws + 77594624);       // 65,536
    bfu* qb   = (bfu*)(ws + 77856768);         // 16,777,216
    bfu* kb   = (bfu*)(ws + 111411200);        // 16,777,216
    bfu* kTb  = (bfu*)(ws + 144965632);        // 16,777,216
    bfu* vTb  = (bfu*)(ws + 178520064);        // 16,777,216  (end 212,074,496)

    rope_table<<<1024, 256, 0, stream>>>(cosT, sinT);
    conv2_bf16<<<2048, 256, 0, stream>>>(x, xb, 4194304, Wqkv, wqb, 3145728);
    // qkv: M=8192, N=6144 -> grid 24*32=768 (768%8==0, swizzle bijective)
    gemm256<0><<<768, 512, 0, stream>>>(xb, wqb, 24, cosT, sinT, qb, kb, kTb, vTb, nullptr);
    conv_bf16<<<1024, 256, 0, stream>>>(Wout, wob, 1048576);   // xb dead now
    kv_outer_mfma<<<512, 256, 0, stream>>>(vTb, kTb, Scb, Zc);
    prefix_Z<<<16, 256, 0, stream>>>(Zc);
    prefix_Sb<<<2048, 256, 0, stream>>>(Scb);
    chunk_mfma<<<dim3(2, 512), 256, 0, stream>>>(qb, kb, vTb, Scb, Zc, ao);
    // out: M=8192, N=2048 -> grid 8*32=256 (256%8==0)
    gemm256<1><<<256, 512, 0, stream>>>(ao, wob, 8, nullptr, nullptr, nullptr, nullptr, nullptr, nullptr, out);
}